// Round 4
// baseline (2221.593 us; speedup 1.0000x reference)
//
#include <hip/hip_runtime.h>
#include <hip/hip_bf16.h>

#define DEVINL __device__ __forceinline__

constexpr int Bsz = 4096, INF = 1024, H1 = 2048, H2 = 2048, OUTD = 512, NE = 8, G = 256;

typedef __attribute__((ext_vector_type(8))) short bf16x8;
typedef __attribute__((ext_vector_type(4))) float f32x4;

DEVINL unsigned short f2bf(float f) {  // RNE f32 -> bf16 bits
  unsigned int u = __float_as_uint(f);
  u = (u + 0x7FFFu + ((u >> 16) & 1u)) >> 16;
  return (unsigned short)u;
}
DEVINL float bf2f(unsigned short h) { return __uint_as_float((unsigned int)h << 16); }

DEVINL void gload16(const void* g, void* l) {
  __builtin_amdgcn_global_load_lds(
      (const __attribute__((address_space(1))) void*)g,
      (__attribute__((address_space(3))) void*)l, 16, 0, 0);
}

DEVINL float waveAllSum(float v) {
#pragma unroll
  for (int m = 32; m > 0; m >>= 1) v += __shfl_xor(v, m, 64);
  return v;
}

// ---------------- pack x -> hi/lo bf16 (row-major) ----------------
__global__ __launch_bounds__(256) void pack_act(const float* __restrict__ in,
                                                unsigned short* __restrict__ hi,
                                                unsigned short* __restrict__ lo) {
  size_t i = ((size_t)blockIdx.x * 256 + threadIdx.x) * 4;
  float4 v = *(const float4*)&in[i];
  short4 h, l;
  h.x = f2bf(v.x); l.x = f2bf(v.x - bf2f(h.x));
  h.y = f2bf(v.y); l.y = f2bf(v.y - bf2f(h.y));
  h.z = f2bf(v.z); l.z = f2bf(v.z - bf2f(h.z));
  h.w = f2bf(v.w); l.w = f2bf(v.w - bf2f(h.w));
  *(short4*)&hi[i] = h;
  *(short4*)&lo[i] = l;
}

// ---------------- pack W[e][K][N] f32 -> Wt hi/lo bf16 [e][N][K] ----------------
__global__ __launch_bounds__(256) void pack_wt(const float* __restrict__ W,
                                               unsigned short* __restrict__ Th,
                                               unsigned short* __restrict__ Tl,
                                               int K, int N) {
  __shared__ float t[32][33];
  const int e = blockIdx.z;
  W += (size_t)e * K * N;
  Th += (size_t)e * N * K;
  Tl += (size_t)e * N * K;
  const int n0 = blockIdx.x * 32, k0 = blockIdx.y * 32;
  const int r = threadIdx.x >> 3, c = (threadIdx.x & 7) * 4;
  float4 v = *(const float4*)&W[(size_t)(k0 + r) * N + n0 + c];
  t[r][c + 0] = v.x; t[r][c + 1] = v.y; t[r][c + 2] = v.z; t[r][c + 3] = v.w;
  __syncthreads();
  float o0 = t[c + 0][r], o1 = t[c + 1][r], o2 = t[c + 2][r], o3 = t[c + 3][r];
  short4 h, l;
  h.x = f2bf(o0); l.x = f2bf(o0 - bf2f(h.x));
  h.y = f2bf(o1); l.y = f2bf(o1 - bf2f(h.y));
  h.z = f2bf(o2); l.z = f2bf(o2 - bf2f(h.z));
  h.w = f2bf(o3); l.w = f2bf(o3 - bf2f(h.w));
  *(short4*)&Th[(size_t)(n0 + r) * K + k0 + c] = h;
  *(short4*)&Tl[(size_t)(n0 + r) * K + k0 + c] = l;
}

// ---------------- bf16x3 MFMA GEMM, double-buffered LDS ----------------
// C[e][M][N] = act(A[e] @ B[e]^T + bias[e]); A hi/lo row-major [M][K],
// Bt hi/lo [N][K]. 128x128 tile, BK=32, 4 waves, 16x16x32 bf16 MFMA.
// LDS: 2 buffers x {4 parts x 8 frags x 1KB} (fragment-packed, lane-linear).
// 2-phase schedule: STAGE(next) issued before compute(cur); single barrier/step.
template <int RELU, int OUTF32>
__global__ __launch_bounds__(256) void gemm_bf16x3(
    const unsigned short* __restrict__ Ahi, const unsigned short* __restrict__ Alo,
    const unsigned short* __restrict__ Bhi, const unsigned short* __restrict__ Blo,
    const float* __restrict__ bias,
    unsigned short* __restrict__ Chi, unsigned short* __restrict__ Clo,
    float* __restrict__ Cf, int M, int N, int K, size_t strideAe) {
  const int e = blockIdx.z;
  Ahi += (size_t)e * strideAe;
  Alo += (size_t)e * strideAe;
  Bhi += (size_t)e * (size_t)N * K;
  Blo += (size_t)e * (size_t)N * K;
  bias += (size_t)e * N;
  if (OUTF32) Cf += (size_t)e * (size_t)M * N;
  else { Chi += (size_t)e * (size_t)M * N; Clo += (size_t)e * (size_t)M * N; }

  const int bm = blockIdx.y * 128, bn = blockIdx.x * 128;
  __shared__ unsigned short lds[2][16384];  // 2 x 32KB
  char* ldsb = (char*)lds;
  const int lane = threadIdx.x & 63, wid = threadIdx.x >> 6;
  const int wr = wid >> 1, wc = wid & 1;
  const int l15 = lane & 15, l4 = lane >> 4;

  // staging role: wave 0->Ahi, 1->Alo, 2->Bhi, 3->Blo (8 frags each)
  const unsigned short* sb;
  int t0;
  if (wid == 0)      { sb = Ahi; t0 = bm; }
  else if (wid == 1) { sb = Alo; t0 = bm; }
  else if (wid == 2) { sb = Bhi; t0 = bn; }
  else               { sb = Blo; t0 = bn; }
  const unsigned short* gp0 = sb + (size_t)(t0 + l15) * K + l4 * 8;
  char* ldsw = ldsb + wid * 8192;  // this wave's part, within buffer 0

  f32x4 acc[4][4];
#pragma unroll
  for (int i = 0; i < 4; ++i)
#pragma unroll
    for (int j = 0; j < 4; ++j) acc[i][j] = (f32x4){0.f, 0.f, 0.f, 0.f};

  // prologue: stage K-tile 0 into buffer 0
#pragma unroll
  for (int f = 0; f < 8; ++f)
    gload16(gp0 + (size_t)(f * 16) * K, ldsw + f * 1024);

  int cur = 0;
  for (int k0 = 0; k0 < K; k0 += 32) {
    __syncthreads();  // stage(cur) landed; prior reads of cur^1 drained
    if (k0 + 32 < K) {  // issue next-tile loads into the other buffer
      const unsigned short* gp = gp0 + k0 + 32;
      char* dst = ldsw + (cur ^ 1) * 32768;
#pragma unroll
      for (int f = 0; f < 8; ++f)
        gload16(gp + (size_t)(f * 16) * K, dst + f * 1024);
    }
    const char* rb = ldsb + cur * 32768;
    bf16x8 ah[4], al[4], bh[4], bl[4];
#pragma unroll
    for (int i = 0; i < 4; ++i) {
      ah[i] = *(const bf16x8*)(rb + 0     + (wr * 4 + i) * 1024 + lane * 16);
      al[i] = *(const bf16x8*)(rb + 8192  + (wr * 4 + i) * 1024 + lane * 16);
      bh[i] = *(const bf16x8*)(rb + 16384 + (wc * 4 + i) * 1024 + lane * 16);
      bl[i] = *(const bf16x8*)(rb + 24576 + (wc * 4 + i) * 1024 + lane * 16);
    }
#pragma unroll
    for (int i = 0; i < 4; ++i)
#pragma unroll
      for (int j = 0; j < 4; ++j) {
        acc[i][j] = __builtin_amdgcn_mfma_f32_16x16x32_bf16(bh[j], ah[i], acc[i][j], 0, 0, 0);
        acc[i][j] = __builtin_amdgcn_mfma_f32_16x16x32_bf16(bl[j], ah[i], acc[i][j], 0, 0, 0);
        acc[i][j] = __builtin_amdgcn_mfma_f32_16x16x32_bf16(bh[j], al[i], acc[i][j], 0, 0, 0);
      }
    cur ^= 1;
  }

  // epilogue: lane holds C[row=bm+wr*64+i*16+l15][col=bn+wc*64+j*16+l4*4+q]
#pragma unroll
  for (int i = 0; i < 4; ++i) {
    const int grow = bm + wr * 64 + i * 16 + l15;
#pragma unroll
    for (int j = 0; j < 4; ++j) {
      const int gcol = bn + wc * 64 + j * 16 + l4 * 4;
      const float4 bb = *(const float4*)&bias[gcol];
      float v0 = acc[i][j][0] + bb.x, v1 = acc[i][j][1] + bb.y;
      float v2 = acc[i][j][2] + bb.z, v3 = acc[i][j][3] + bb.w;
      if (RELU) {
        v0 = fmaxf(v0, 0.f); v1 = fmaxf(v1, 0.f);
        v2 = fmaxf(v2, 0.f); v3 = fmaxf(v3, 0.f);
      }
      if (OUTF32) {
        *(float4*)&Cf[(size_t)grow * N + gcol] = make_float4(v0, v1, v2, v3);
      } else {
        short4 h, l;
        h.x = f2bf(v0); l.x = f2bf(v0 - bf2f(h.x));
        h.y = f2bf(v1); l.y = f2bf(v1 - bf2f(h.y));
        h.z = f2bf(v2); l.z = f2bf(v2 - bf2f(h.z));
        h.w = f2bf(v3); l.w = f2bf(v3 - bf2f(h.w));
        *(short4*)&Chi[(size_t)grow * N + gcol] = h;
        *(short4*)&Clo[(size_t)grow * N + gcol] = l;
      }
    }
  }
}

// ---------------- gate layer 1 ----------------
__global__ __launch_bounds__(256) void gate1_kernel(
    const float* __restrict__ x, const float* __restrict__ Wg1,
    const float* __restrict__ bg1, float* __restrict__ g) {
  __shared__ float xs[8 * 1024];
  const int b0 = blockIdx.x * 8;
  const float* xp = x + (size_t)b0 * INF;
  for (int idx = threadIdx.x * 4; idx < 8 * 1024; idx += 1024)
    *(float4*)&xs[idx] = *(const float4*)&xp[idx];
  __syncthreads();
  const int t = threadIdx.x;
  float acc[8] = {0, 0, 0, 0, 0, 0, 0, 0};
  for (int i = 0; i < INF; ++i) {
    float w = Wg1[(size_t)i * G + t];
#pragma unroll
    for (int r = 0; r < 8; ++r) acc[r] = fmaf(xs[r * 1024 + i], w, acc[r]);
  }
  const float bb = bg1[t];
#pragma unroll
  for (int r = 0; r < 8; ++r)
    g[(size_t)(b0 + r) * G + t] = fmaxf(acc[r] + bb, 0.0f);
}

// ---------------- gate layer 2 + softmax ----------------
__global__ __launch_bounds__(64) void gate2_kernel(
    const float* __restrict__ g, const float* __restrict__ Wg2,
    const float* __restrict__ bg2, float* __restrict__ gw) {
  const int b = blockIdx.x, lane = threadIdx.x;
  float4 gv = *(const float4*)(g + (size_t)b * G + lane * 4);
  float p[8];
#pragma unroll
  for (int e = 0; e < 8; ++e) {
    int j = lane * 4;
    float s = gv.x * Wg2[(j + 0) * 8 + e] + gv.y * Wg2[(j + 1) * 8 + e] +
              gv.z * Wg2[(j + 2) * 8 + e] + gv.w * Wg2[(j + 3) * 8 + e];
    p[e] = waveAllSum(s);
  }
  if (lane == 0) {
    float l[8];
    float mx = -1e30f;
#pragma unroll
    for (int e = 0; e < 8; ++e) {
      l[e] = p[e] + bg2[e];
      mx = fmaxf(mx, l[e]);
    }
    float sum = 0.0f;
#pragma unroll
    for (int e = 0; e < 8; ++e) {
      l[e] = expf(l[e] - mx);
      sum += l[e];
    }
    float inv = 1.0f / sum;
#pragma unroll
    for (int e = 0; e < 8; ++e) gw[(size_t)b * 8 + e] = l[e] * inv;
  }
}

// ---------------- Gram-Schmidt + combine + out-proj ----------------
__global__ __launch_bounds__(256) void gs_kernel(
    const float* __restrict__ eo, const float* __restrict__ gw,
    const float* __restrict__ Wo, const float* __restrict__ bo,
    float* __restrict__ out, int CB) {
  const int lane = threadIdx.x & 63;
  const int b = blockIdx.x * 4 + (threadIdx.x >> 6);
  const size_t ES = (size_t)CB * OUTD;
  const float* base = eo + (size_t)b * OUTD + lane * 8;
  float vs[8][8];
  float denom[8];
#pragma unroll
  for (int i = 0; i < 8; ++i) {
    float cur[8];
    float4 u0 = *(const float4*)(base + (size_t)i * ES);
    float4 u1 = *(const float4*)(base + (size_t)i * ES + 4);
    cur[0] = u0.x; cur[1] = u0.y; cur[2] = u0.z; cur[3] = u0.w;
    cur[4] = u1.x; cur[5] = u1.y; cur[6] = u1.z; cur[7] = u1.w;
#pragma unroll
    for (int j = 0; j < i; ++j) {
      float dp = 0.0f;
#pragma unroll
      for (int d = 0; d < 8; ++d) dp = fmaf(cur[d], vs[j][d], dp);
      dp = waveAllSum(dp);
      float coeff = dp / (denom[j] + 1e-6f);
#pragma unroll
      for (int d = 0; d < 8; ++d) cur[d] = fmaf(-coeff, vs[j][d], cur[d]);
    }
    float nn = 0.0f;
#pragma unroll
    for (int d = 0; d < 8; ++d) nn = fmaf(cur[d], cur[d], nn);
    nn = waveAllSum(nn);
    float inv = 1.0f / fmaxf(sqrtf(nn), 1e-6f);
#pragma unroll
    for (int d = 0; d < 8; ++d) vs[i][d] = cur[d] * inv;
    float dd = 0.0f;
#pragma unroll
    for (int d = 0; d < 8; ++d) dd = fmaf(vs[i][d], vs[i][d], dd);
    denom[i] = waveAllSum(dd);
  }
  float gwv[8];
#pragma unroll
  for (int e = 0; e < 8; ++e) gwv[e] = gw[(size_t)b * 8 + e];
  float part = 0.0f;
#pragma unroll
  for (int d = 0; d < 8; ++d) {
    float c = 0.0f;
#pragma unroll
    for (int e = 0; e < 8; ++e) c = fmaf(vs[e][d], gwv[e], c);
    part = fmaf(c, Wo[lane * 8 + d], part);
  }
  part = waveAllSum(part);
  if (lane == 0) out[b] = part + bo[0];
}

extern "C" void kernel_launch(void* const* d_in, const int* in_sizes, int n_in,
                              void* d_out, int out_size, void* d_ws, size_t ws_size,
                              hipStream_t stream) {
  const float* x   = (const float*)d_in[0];
  const float* W1  = (const float*)d_in[1];
  const float* b1  = (const float*)d_in[2];
  const float* W2  = (const float*)d_in[3];
  const float* b2  = (const float*)d_in[4];
  const float* W3  = (const float*)d_in[5];
  const float* b3  = (const float*)d_in[6];
  const float* Wg1 = (const float*)d_in[7];
  const float* bg1 = (const float*)d_in[8];
  const float* Wg2 = (const float*)d_in[9];
  const float* bg2 = (const float*)d_in[10];
  const float* Wo  = (const float*)d_in[11];
  const float* bo  = (const float*)d_in[12];
  float* out = (float*)d_out;

  typedef unsigned short u16;
  char* p = (char*)d_ws;
  float* gw = (float*)p;          p += (size_t)(128u << 10);
  float* g  = (float*)p;          p += (size_t)(4u << 20);
  u16* xhi = (u16*)p;             p += (size_t)Bsz * INF * 2;
  u16* xlo = (u16*)p;             p += (size_t)Bsz * INF * 2;
  u16* w1h = (u16*)p;             p += (size_t)NE * H1 * INF * 2;
  u16* w1l = (u16*)p;             p += (size_t)NE * H1 * INF * 2;
  u16* w2h = (u16*)p;             p += (size_t)NE * H2 * H1 * 2;
  u16* w2l = (u16*)p;             p += (size_t)NE * H2 * H1 * 2;
  u16* w3h = (u16*)p;             p += (size_t)NE * OUTD * H2 * 2;
  u16* w3l = (u16*)p;             p += (size_t)NE * OUTD * H2 * 2;
  const size_t fixedBytes = (size_t)(p - (char*)d_ws);

  // chunk region: h1 hi/lo (CB*32KB each) + h2 hi/lo (CB*32KB each) = CB*128KB
  int CB = 4096;
  while (CB > 128 && fixedBytes + (size_t)CB * (size_t)(128u << 10) > ws_size) CB >>= 1;
  u16* h1h = (u16*)p;
  u16* h1l = h1h + (size_t)NE * CB * H1;
  u16* h2h = h1l + (size_t)NE * CB * H1;
  u16* h2l = h2h + (size_t)NE * CB * H2;
  float* eo = (float*)h1h;  // layer-3 f32 out reuses h1 region (dead by then)

  hipMemsetAsync(d_out, 0, (size_t)out_size * sizeof(float), stream);

  // pack inputs/weights (once)
  pack_act<<<(Bsz * INF) / 1024, 256, 0, stream>>>(x, xhi, xlo);
  pack_wt<<<dim3(H1 / 32, INF / 32, NE), 256, 0, stream>>>(W1, w1h, w1l, INF, H1);
  pack_wt<<<dim3(H2 / 32, H1 / 32, NE), 256, 0, stream>>>(W2, w2h, w2l, H1, H2);
  pack_wt<<<dim3(OUTD / 32, H2 / 32, NE), 256, 0, stream>>>(W3, w3h, w3l, H2, OUTD);

  gate1_kernel<<<Bsz / 8, 256, 0, stream>>>(x, Wg1, bg1, g);
  gate2_kernel<<<Bsz, 64, 0, stream>>>(g, Wg2, bg2, gw);

  for (int c0 = 0; c0 < Bsz; c0 += CB) {
    gemm_bf16x3<1, 0><<<dim3(H1 / 128, CB / 128, NE), 256, 0, stream>>>(
        xhi + (size_t)c0 * INF, xlo + (size_t)c0 * INF, w1h, w1l, b1,
        h1h, h1l, nullptr, CB, H1, INF, (size_t)0);
    gemm_bf16x3<1, 0><<<dim3(H2 / 128, CB / 128, NE), 256, 0, stream>>>(
        h1h, h1l, w2h, w2l, b2, h2h, h2l, nullptr, CB, H2, H1, (size_t)CB * H1);
    gemm_bf16x3<0, 1><<<dim3(OUTD / 128, CB / 128, NE), 256, 0, stream>>>(
        h2h, h2l, w3h, w3l, b3, nullptr, nullptr, eo, CB, OUTD, H2, (size_t)CB * H2);
    gs_kernel<<<CB / 4, 256, 0, stream>>>(eo, gw + (size_t)c0 * NE, Wo, bo,
                                          out + c0, CB);
  }
}

// Round 5
// 1737.010 us; speedup vs baseline: 1.2790x; 1.2790x over previous
//
#include <hip/hip_runtime.h>
#include <hip/hip_bf16.h>

#define DEVINL __device__ __forceinline__

constexpr int Bsz = 4096, INF = 1024, H1 = 2048, H2 = 2048, OUTD = 512, NE = 8, G = 256;

typedef __attribute__((ext_vector_type(8))) short bf16x8;
typedef __attribute__((ext_vector_type(4))) float f32x4;

DEVINL unsigned short f2bf(float f) {  // RNE f32 -> bf16 bits
  unsigned int u = __float_as_uint(f);
  u = (u + 0x7FFFu + ((u >> 16) & 1u)) >> 16;
  return (unsigned short)u;
}
DEVINL float bf2f(unsigned short h) { return __uint_as_float((unsigned int)h << 16); }

DEVINL void gload16(const void* g, void* l) {
  __builtin_amdgcn_global_load_lds(
      (const __attribute__((address_space(1))) void*)g,
      (__attribute__((address_space(3))) void*)l, 16, 0, 0);
}

DEVINL float waveAllSum(float v) {
#pragma unroll
  for (int m = 32; m > 0; m >>= 1) v += __shfl_xor(v, m, 64);
  return v;
}

// ---------------- pack x -> hi/lo bf16 (row-major) ----------------
__global__ __launch_bounds__(256) void pack_act(const float* __restrict__ in,
                                                unsigned short* __restrict__ hi,
                                                unsigned short* __restrict__ lo) {
  size_t i = ((size_t)blockIdx.x * 256 + threadIdx.x) * 4;
  float4 v = *(const float4*)&in[i];
  short4 h, l;
  h.x = f2bf(v.x); l.x = f2bf(v.x - bf2f(h.x));
  h.y = f2bf(v.y); l.y = f2bf(v.y - bf2f(h.y));
  h.z = f2bf(v.z); l.z = f2bf(v.z - bf2f(h.z));
  h.w = f2bf(v.w); l.w = f2bf(v.w - bf2f(h.w));
  *(short4*)&hi[i] = h;
  *(short4*)&lo[i] = l;
}

// ---------------- pack W[e][K][N] f32 -> Wt hi/lo bf16 [e][N][K] ----------------
__global__ __launch_bounds__(256) void pack_wt(const float* __restrict__ W,
                                               unsigned short* __restrict__ Th,
                                               unsigned short* __restrict__ Tl,
                                               int K, int N) {
  __shared__ float t[32][33];
  const int e = blockIdx.z;
  W += (size_t)e * K * N;
  Th += (size_t)e * N * K;
  Tl += (size_t)e * N * K;
  const int n0 = blockIdx.x * 32, k0 = blockIdx.y * 32;
  const int r = threadIdx.x >> 3, c = (threadIdx.x & 7) * 4;
  float4 v = *(const float4*)&W[(size_t)(k0 + r) * N + n0 + c];
  t[r][c + 0] = v.x; t[r][c + 1] = v.y; t[r][c + 2] = v.z; t[r][c + 3] = v.w;
  __syncthreads();
  float o0 = t[c + 0][r], o1 = t[c + 1][r], o2 = t[c + 2][r], o3 = t[c + 3][r];
  short4 h, l;
  h.x = f2bf(o0); l.x = f2bf(o0 - bf2f(h.x));
  h.y = f2bf(o1); l.y = f2bf(o1 - bf2f(h.y));
  h.z = f2bf(o2); l.z = f2bf(o2 - bf2f(h.z));
  h.w = f2bf(o3); l.w = f2bf(o3 - bf2f(h.w));
  *(short4*)&Th[(size_t)(n0 + r) * K + k0 + c] = h;
  *(short4*)&Tl[(size_t)(n0 + r) * K + k0 + c] = l;
}

// ---------------- bf16x3 MFMA GEMM, 256x256 tile, double-buffered ----------------
// C[e][M][N] = act(A[e] @ B[e]^T + bias[e]); A hi/lo row-major [M][K],
// Bt hi/lo [N][K]. BK=32, 8 waves (2m x 4n), wave tile 128x64.
// LDS per buffer (64KB): [Ahi 16K][Alo 16K][Bhi 16K][Blo 16K], frag-packed
// (16 frags x 1KB, lane-linear; frag = 16 rows x 32 k). 2 buffers = 128KB.
// Staging: wave w stages half a section: sec=w>>1, half=w&1 (8 frags x 1KB).
// 2-phase: barrier -> STAGE(next, buf^1) -> ds_read+MFMA(buf) -> flip.
template <int RELU, int OUTF32>
__global__ __launch_bounds__(512) void gemm_bf16x3_256(
    const unsigned short* __restrict__ Ahi, const unsigned short* __restrict__ Alo,
    const unsigned short* __restrict__ Bhi, const unsigned short* __restrict__ Blo,
    const float* __restrict__ bias,
    unsigned short* __restrict__ Chi, unsigned short* __restrict__ Clo,
    float* __restrict__ Cf, int M, int N, int K, size_t strideAe) {
  const int e = blockIdx.z;
  Ahi += (size_t)e * strideAe;
  Alo += (size_t)e * strideAe;
  Bhi += (size_t)e * (size_t)N * K;
  Blo += (size_t)e * (size_t)N * K;
  bias += (size_t)e * N;
  if (OUTF32) Cf += (size_t)e * (size_t)M * N;
  else { Chi += (size_t)e * (size_t)M * N; Clo += (size_t)e * (size_t)M * N; }

  const int bm = blockIdx.y * 256, bn = blockIdx.x * 256;
  __shared__ char ldsb[2 * 65536];  // 128KB
  const int lane = threadIdx.x & 63, wid = threadIdx.x >> 6;
  const int wm = wid >> 2, wn = wid & 3;
  const int l15 = lane & 15, l4 = lane >> 4;

  // staging role
  const int sec = wid >> 1, half = wid & 1;
  const unsigned short* sb = (sec == 0) ? Ahi : (sec == 1) ? Alo : (sec == 2) ? Bhi : Blo;
  const int t0 = (sec < 2) ? bm : bn;
  const unsigned short* gp0 = sb + (size_t)(t0 + half * 128 + l15) * K + l4 * 8;
  char* ldsw = ldsb + sec * 16384 + half * 8192;

  f32x4 acc[8][4];
#pragma unroll
  for (int i = 0; i < 8; ++i)
#pragma unroll
    for (int j = 0; j < 4; ++j) acc[i][j] = (f32x4){0.f, 0.f, 0.f, 0.f};

  // prologue: stage K-tile 0 into buffer 0
#pragma unroll
  for (int f = 0; f < 8; ++f)
    gload16(gp0 + (size_t)(f * 16) * K, ldsw + f * 1024);

  int cur = 0;
  for (int k0 = 0; k0 < K; k0 += 32) {
    __syncthreads();  // stage(cur) landed (vmcnt drain); prior reads of cur^1 done
    if (k0 + 32 < K) {  // issue next-tile loads into the other buffer
      const unsigned short* gp = gp0 + k0 + 32;
      char* dst = ldsw + (cur ^ 1) * 65536;
#pragma unroll
      for (int f = 0; f < 8; ++f)
        gload16(gp + (size_t)(f * 16) * K, dst + f * 1024);
    }
    const char* rb = ldsb + cur * 65536;
    bf16x8 bh[4], bl[4];
#pragma unroll
    for (int j = 0; j < 4; ++j) {
      bh[j] = *(const bf16x8*)(rb + 32768 + (wn * 4 + j) * 1024 + lane * 16);
      bl[j] = *(const bf16x8*)(rb + 49152 + (wn * 4 + j) * 1024 + lane * 16);
    }
#pragma unroll
    for (int i = 0; i < 8; ++i) {
      bf16x8 ah = *(const bf16x8*)(rb + (wm * 8 + i) * 1024 + lane * 16);
      bf16x8 al = *(const bf16x8*)(rb + 16384 + (wm * 8 + i) * 1024 + lane * 16);
#pragma unroll
      for (int j = 0; j < 4; ++j) {
        acc[i][j] = __builtin_amdgcn_mfma_f32_16x16x32_bf16(bh[j], ah, acc[i][j], 0, 0, 0);
        acc[i][j] = __builtin_amdgcn_mfma_f32_16x16x32_bf16(bl[j], ah, acc[i][j], 0, 0, 0);
        acc[i][j] = __builtin_amdgcn_mfma_f32_16x16x32_bf16(bh[j], al, acc[i][j], 0, 0, 0);
      }
    }
    cur ^= 1;
  }

  // epilogue: lane holds C[row=bm+wm*128+i*16+l15][col=bn+wn*64+j*16+l4*4+q]
#pragma unroll
  for (int i = 0; i < 8; ++i) {
    const int grow = bm + wm * 128 + i * 16 + l15;
#pragma unroll
    for (int j = 0; j < 4; ++j) {
      const int gcol = bn + wn * 64 + j * 16 + l4 * 4;
      const float4 bb = *(const float4*)&bias[gcol];
      float v0 = acc[i][j][0] + bb.x, v1 = acc[i][j][1] + bb.y;
      float v2 = acc[i][j][2] + bb.z, v3 = acc[i][j][3] + bb.w;
      if (RELU) {
        v0 = fmaxf(v0, 0.f); v1 = fmaxf(v1, 0.f);
        v2 = fmaxf(v2, 0.f); v3 = fmaxf(v3, 0.f);
      }
      if (OUTF32) {
        *(float4*)&Cf[(size_t)grow * N + gcol] = make_float4(v0, v1, v2, v3);
      } else {
        short4 h, l;
        h.x = f2bf(v0); l.x = f2bf(v0 - bf2f(h.x));
        h.y = f2bf(v1); l.y = f2bf(v1 - bf2f(h.y));
        h.z = f2bf(v2); l.z = f2bf(v2 - bf2f(h.z));
        h.w = f2bf(v3); l.w = f2bf(v3 - bf2f(h.w));
        *(short4*)&Chi[(size_t)grow * N + gcol] = h;
        *(short4*)&Clo[(size_t)grow * N + gcol] = l;
      }
    }
  }
}

// ---------------- gate layer 1 ----------------
__global__ __launch_bounds__(256) void gate1_kernel(
    const float* __restrict__ x, const float* __restrict__ Wg1,
    const float* __restrict__ bg1, float* __restrict__ g) {
  __shared__ float xs[8 * 1024];
  const int b0 = blockIdx.x * 8;
  const float* xp = x + (size_t)b0 * INF;
  for (int idx = threadIdx.x * 4; idx < 8 * 1024; idx += 1024)
    *(float4*)&xs[idx] = *(const float4*)&xp[idx];
  __syncthreads();
  const int t = threadIdx.x;
  float acc[8] = {0, 0, 0, 0, 0, 0, 0, 0};
  for (int i = 0; i < INF; ++i) {
    float w = Wg1[(size_t)i * G + t];
#pragma unroll
    for (int r = 0; r < 8; ++r) acc[r] = fmaf(xs[r * 1024 + i], w, acc[r]);
  }
  const float bb = bg1[t];
#pragma unroll
  for (int r = 0; r < 8; ++r)
    g[(size_t)(b0 + r) * G + t] = fmaxf(acc[r] + bb, 0.0f);
}

// ---------------- gate layer 2 + softmax ----------------
__global__ __launch_bounds__(64) void gate2_kernel(
    const float* __restrict__ g, const float* __restrict__ Wg2,
    const float* __restrict__ bg2, float* __restrict__ gw) {
  const int b = blockIdx.x, lane = threadIdx.x;
  float4 gv = *(const float4*)(g + (size_t)b * G + lane * 4);
  float p[8];
#pragma unroll
  for (int e = 0; e < 8; ++e) {
    int j = lane * 4;
    float s = gv.x * Wg2[(j + 0) * 8 + e] + gv.y * Wg2[(j + 1) * 8 + e] +
              gv.z * Wg2[(j + 2) * 8 + e] + gv.w * Wg2[(j + 3) * 8 + e];
    p[e] = waveAllSum(s);
  }
  if (lane == 0) {
    float l[8];
    float mx = -1e30f;
#pragma unroll
    for (int e = 0; e < 8; ++e) {
      l[e] = p[e] + bg2[e];
      mx = fmaxf(mx, l[e]);
    }
    float sum = 0.0f;
#pragma unroll
    for (int e = 0; e < 8; ++e) {
      l[e] = expf(l[e] - mx);
      sum += l[e];
    }
    float inv = 1.0f / sum;
#pragma unroll
    for (int e = 0; e < 8; ++e) gw[(size_t)b * 8 + e] = l[e] * inv;
  }
}

// ---------------- Gram-Schmidt + combine + out-proj ----------------
__global__ __launch_bounds__(256) void gs_kernel(
    const float* __restrict__ eo, const float* __restrict__ gw,
    const float* __restrict__ Wo, const float* __restrict__ bo,
    float* __restrict__ out, int CB) {
  const int lane = threadIdx.x & 63;
  const int b = blockIdx.x * 4 + (threadIdx.x >> 6);
  const size_t ES = (size_t)CB * OUTD;
  const float* base = eo + (size_t)b * OUTD + lane * 8;
  float vs[8][8];
  float denom[8];
#pragma unroll
  for (int i = 0; i < 8; ++i) {
    float cur[8];
    float4 u0 = *(const float4*)(base + (size_t)i * ES);
    float4 u1 = *(const float4*)(base + (size_t)i * ES + 4);
    cur[0] = u0.x; cur[1] = u0.y; cur[2] = u0.z; cur[3] = u0.w;
    cur[4] = u1.x; cur[5] = u1.y; cur[6] = u1.z; cur[7] = u1.w;
#pragma unroll
    for (int j = 0; j < i; ++j) {
      float dp = 0.0f;
#pragma unroll
      for (int d = 0; d < 8; ++d) dp = fmaf(cur[d], vs[j][d], dp);
      dp = waveAllSum(dp);
      float coeff = dp / (denom[j] + 1e-6f);
#pragma unroll
      for (int d = 0; d < 8; ++d) cur[d] = fmaf(-coeff, vs[j][d], cur[d]);
    }
    float nn = 0.0f;
#pragma unroll
    for (int d = 0; d < 8; ++d) nn = fmaf(cur[d], cur[d], nn);
    nn = waveAllSum(nn);
    float inv = 1.0f / fmaxf(sqrtf(nn), 1e-6f);
#pragma unroll
    for (int d = 0; d < 8; ++d) vs[i][d] = cur[d] * inv;
    float dd = 0.0f;
#pragma unroll
    for (int d = 0; d < 8; ++d) dd = fmaf(vs[i][d], vs[i][d], dd);
    denom[i] = waveAllSum(dd);
  }
  float gwv[8];
#pragma unroll
  for (int e = 0; e < 8; ++e) gwv[e] = gw[(size_t)b * 8 + e];
  float part = 0.0f;
#pragma unroll
  for (int d = 0; d < 8; ++d) {
    float c = 0.0f;
#pragma unroll
    for (int e = 0; e < 8; ++e) c = fmaf(vs[e][d], gwv[e], c);
    part = fmaf(c, Wo[lane * 8 + d], part);
  }
  part = waveAllSum(part);
  if (lane == 0) out[b] = part + bo[0];
}

extern "C" void kernel_launch(void* const* d_in, const int* in_sizes, int n_in,
                              void* d_out, int out_size, void* d_ws, size_t ws_size,
                              hipStream_t stream) {
  const float* x   = (const float*)d_in[0];
  const float* W1  = (const float*)d_in[1];
  const float* b1  = (const float*)d_in[2];
  const float* W2  = (const float*)d_in[3];
  const float* b2  = (const float*)d_in[4];
  const float* W3  = (const float*)d_in[5];
  const float* b3  = (const float*)d_in[6];
  const float* Wg1 = (const float*)d_in[7];
  const float* bg1 = (const float*)d_in[8];
  const float* Wg2 = (const float*)d_in[9];
  const float* bg2 = (const float*)d_in[10];
  const float* Wo  = (const float*)d_in[11];
  const float* bo  = (const float*)d_in[12];
  float* out = (float*)d_out;

  typedef unsigned short u16;
  char* p = (char*)d_ws;
  float* gw = (float*)p;          p += (size_t)(128u << 10);
  float* g  = (float*)p;          p += (size_t)(4u << 20);
  u16* xhi = (u16*)p;             p += (size_t)Bsz * INF * 2;
  u16* xlo = (u16*)p;             p += (size_t)Bsz * INF * 2;
  u16* w1h = (u16*)p;             p += (size_t)NE * H1 * INF * 2;
  u16* w1l = (u16*)p;             p += (size_t)NE * H1 * INF * 2;
  u16* w2h = (u16*)p;             p += (size_t)NE * H2 * H1 * 2;
  u16* w2l = (u16*)p;             p += (size_t)NE * H2 * H1 * 2;
  u16* w3h = (u16*)p;             p += (size_t)NE * OUTD * H2 * 2;
  u16* w3l = (u16*)p;             p += (size_t)NE * OUTD * H2 * 2;
  const size_t fixedBytes = (size_t)(p - (char*)d_ws);

  // chunk region: h1 hi/lo + h2 hi/lo = CB*128KB; CB multiple of 256
  int CB = 4096;
  while (CB > 256 && fixedBytes + (size_t)CB * (size_t)(128u << 10) > ws_size) CB >>= 1;
  u16* h1h = (u16*)p;
  u16* h1l = h1h + (size_t)NE * CB * H1;
  u16* h2h = h1l + (size_t)NE * CB * H1;
  u16* h2l = h2h + (size_t)NE * CB * H2;
  float* eo = (float*)h1h;  // layer-3 f32 out reuses h1 region (dead by then)

  hipMemsetAsync(d_out, 0, (size_t)out_size * sizeof(float), stream);

  // pack inputs/weights (once)
  pack_act<<<(Bsz * INF) / 1024, 256, 0, stream>>>(x, xhi, xlo);
  pack_wt<<<dim3(H1 / 32, INF / 32, NE), 256, 0, stream>>>(W1, w1h, w1l, INF, H1);
  pack_wt<<<dim3(H2 / 32, H1 / 32, NE), 256, 0, stream>>>(W2, w2h, w2l, H1, H2);
  pack_wt<<<dim3(OUTD / 32, H2 / 32, NE), 256, 0, stream>>>(W3, w3h, w3l, H2, OUTD);

  gate1_kernel<<<Bsz / 8, 256, 0, stream>>>(x, Wg1, bg1, g);
  gate2_kernel<<<Bsz, 64, 0, stream>>>(g, Wg2, bg2, gw);

  for (int c0 = 0; c0 < Bsz; c0 += CB) {
    gemm_bf16x3_256<1, 0><<<dim3(H1 / 256, CB / 256, NE), 512, 0, stream>>>(
        xhi + (size_t)c0 * INF, xlo + (size_t)c0 * INF, w1h, w1l, b1,
        h1h, h1l, nullptr, CB, H1, INF, (size_t)0);
    gemm_bf16x3_256<1, 0><<<dim3(H2 / 256, CB / 256, NE), 512, 0, stream>>>(
        h1h, h1l, w2h, w2l, b2, h2h, h2l, nullptr, CB, H2, H1, (size_t)CB * H1);
    gemm_bf16x3_256<0, 1><<<dim3(OUTD / 256, CB / 256, NE), 512, 0, stream>>>(
        h2h, h2l, w3h, w3l, b3, nullptr, nullptr, eo, CB, OUTD, H2, (size_t)CB * H2);
    gs_kernel<<<CB / 4, 256, 0, stream>>>(eo, gw + (size_t)c0 * NE, Wo, bo,
                                          out + c0, CB);
  }
}